// Round 2
// baseline (1167.871 us; speedup 1.0000x reference)
//
#include <hip/hip_runtime.h>
#include <hip/hip_bf16.h>
#include <hip/hip_fp16.h>

// Problem: N=4096 nodes, E=4096 hyperedges, F=256, H=256.
// All float tensors are float32; batch_mask is int32.
// out = 8192 float32: [pos_score(4096) | neg_score(4096)].

typedef short bf16x8 __attribute__((ext_vector_type(8)));
typedef float f32x4 __attribute__((ext_vector_type(4)));
typedef unsigned short u16x2 __attribute__((ext_vector_type(2)));

static __device__ __forceinline__ unsigned short f2bf(float f) {
    __hip_bfloat16 b = __float2bfloat16(f);
    return __builtin_bit_cast(unsigned short, b);
}
static __device__ __forceinline__ float f16u_to_f(unsigned u) {
    __half h = __builtin_bit_cast(__half, (unsigned short)(u & 0xffffu));
    return __half2float(h);
}
static __device__ __forceinline__ void pkmaxmin(unsigned& mx, unsigned& mn, unsigned v) {
    u16x2 vv = __builtin_bit_cast(u16x2, v);
    u16x2 a  = __builtin_bit_cast(u16x2, mx);
    u16x2 b  = __builtin_bit_cast(u16x2, mn);
    a = __builtin_elementwise_max(a, vv);   // v_pk_max_u16 (h>=0 => u16-monotonic f16)
    b = __builtin_elementwise_min(b, vv);   // v_pk_min_u16
    mx = __builtin_bit_cast(unsigned, a);
    mn = __builtin_bit_cast(unsigned, b);
}

// ---------------------------------------------------------------- transpose W (f32 -> bf16)
// Wt[n][k] = bf16(W[k][n]), 256x256. grid (256, 2), block 256.
__global__ void k_transpose(const float* __restrict__ Ws, const float* __restrict__ Wh,
                            unsigned short* __restrict__ Wts, unsigned short* __restrict__ Wth) {
    int k = blockIdx.x;
    int n = threadIdx.x;
    const float* W     = blockIdx.y ? Wh : Ws;
    unsigned short* Wt = blockIdx.y ? Wth : Wts;
    Wt[n * 256 + k] = f2bf(W[k * 256 + n]);
}

// ---------------------------------------------------------------- pack mask
// mask [E=4096][N=4096] int32 (0/1) -> packed [E][128] u32 bitwords (LSB = lowest n).
__global__ void k_pack_mask(const int* __restrict__ mask, unsigned* __restrict__ packed) {
    int w = blockIdx.x * 256 + threadIdx.x;       // 0 .. 524287
    const int* p = mask + (size_t)w * 32;
    unsigned word = 0;
#pragma unroll
    for (int j = 0; j < 32; j += 4) {
        int4 m = *(const int4*)(p + j);
        word |= (m.x != 0 ? (1u << j) : 0u)
              | (m.y != 0 ? (1u << (j + 1)) : 0u)
              | (m.z != 0 ? (1u << (j + 2)) : 0u)
              | (m.w != 0 ? (1u << (j + 3)) : 0u);
    }
    packed[w] = word;
}

// ---------------------------------------------------------------- GEMM + relu
// h = relu(Xf @ Ws + Xm @ Wh + b_self + b_hyper), stored f16.
// MFMA 16x16x32 bf16; A fragment converted f32->bf16 in-register; B from
// pre-transposed bf16 Wt rows (16B contiguous). Tile 64(m) x 64(n), 4 waves.
// grid (64, 4, 2).
__launch_bounds__(256)
__global__ void k_gemm_relu(const float* __restrict__ pXf, const float* __restrict__ pXm,
                            const float* __restrict__ nXf, const float* __restrict__ nXm,
                            const unsigned short* __restrict__ Wts, const unsigned short* __restrict__ Wth,
                            const float* __restrict__ bs,  const float* __restrict__ bh,
                            unsigned short* __restrict__ hAll /* f16 [2][4096][256] */) {
    const int t  = threadIdx.x;
    const int wv = t >> 6;
    const int l  = t & 63;
    const int lm = l & 15;
    const int q  = l >> 4;
    const int bz = blockIdx.z;
    const float* Xf = bz ? nXf : pXf;
    const float* Xm = bz ? nXm : pXm;
    unsigned short* hb = hAll + (size_t)bz * 4096 * 256;

    const int m0 = blockIdx.x * 64 + wv * 16;
    const int n0 = blockIdx.y * 64;

    f32x4 acc[4] = {};
#pragma unroll
    for (int ks = 0; ks < 512; ks += 32) {
        const float* X           = (ks < 256) ? Xf : Xm;
        const unsigned short* Wt = (ks < 256) ? Wts : Wth;
        const int kk = (ks & 255) + q * 8;
        float4 a0 = *(const float4*)(X + (m0 + lm) * 256 + kk);
        float4 a1 = *(const float4*)(X + (m0 + lm) * 256 + kk + 4);
        bf16x8 a;
        a[0] = (short)f2bf(a0.x); a[1] = (short)f2bf(a0.y);
        a[2] = (short)f2bf(a0.z); a[3] = (short)f2bf(a0.w);
        a[4] = (short)f2bf(a1.x); a[5] = (short)f2bf(a1.y);
        a[6] = (short)f2bf(a1.z); a[7] = (short)f2bf(a1.w);
#pragma unroll
        for (int nt = 0; nt < 4; nt++) {
            bf16x8 b = *(const bf16x8*)(Wt + (n0 + nt * 16 + lm) * 256 + kk);
            acc[nt] = __builtin_amdgcn_mfma_f32_16x16x32_bf16(a, b, acc[nt], 0, 0, 0);
        }
    }
    // C/D layout: col = lane&15, row = (lane>>4)*4 + reg  [m89/m91 verified]
#pragma unroll
    for (int nt = 0; nt < 4; nt++) {
        const int c = n0 + nt * 16 + lm;
        const float bsum = bs[c] + bh[c];
#pragma unroll
        for (int i = 0; i < 4; i++) {
            const int r = m0 + q * 4 + i;
            float v = acc[nt][i] + bsum;
            v = v > 0.f ? v : 0.f;   // relu => h >= +0.0
            hb[r * 256 + c] = __builtin_bit_cast(unsigned short, __float2half(v));
        }
    }
}

// ---------------------------------------------------------------- pool + score
// Per block: 16 hyperedges, one branch. 4 waves; wave wv owns edges e0+wv*4..+3
// (wave-uniform mask words -> scalar-branch skipping, ~50% density) and ALL
// 256 h-cols (lane l holds cols 4l..4l+3 as two packed-u16 pairs).
// h chunk (64 nodes x 256 cols f16 = 32KB) staged in LDS per iteration.
// Epilogue fuses (max-min) . W_score + sigmoid via wave shuffle-reduce.
// grid (256, 2), block 256. LDS 40KB.
__launch_bounds__(256)
__global__ void k_pool_score(const unsigned short* __restrict__ hAll,
                             const unsigned* __restrict__ packed,
                             const float* __restrict__ Wscore,
                             const float* __restrict__ bscore,
                             float* __restrict__ out) {
    __shared__ __align__(16) unsigned bits[16 * 128];          // 8 KB
    __shared__ __align__(16) unsigned short hch[64 * 256];     // 32 KB

    const int t  = threadIdx.x;
    const int wv = t >> 6;
    const int l  = t & 63;
    const int br = blockIdx.y;
    const int e0 = blockIdx.x * 16;
    const unsigned short* h = hAll + (size_t)br * 4096 * 256;

    {   // bits for the 16 edges of this block: 2048 contiguous u32
        const uint4* src = (const uint4*)(packed + e0 * 128);
        uint4* dst = (uint4*)bits;
        dst[t]       = src[t];
        dst[t + 256] = src[t + 256];
    }

    unsigned mx[4][2], mn[4][2];
#pragma unroll
    for (int e = 0; e < 4; e++) {
        mx[e][0] = 0u;          mx[e][1] = 0u;            // identity: +0.0 (h >= 0)
        mn[e][0] = 0x7C007C00u; mn[e][1] = 0x7C007C00u;   // +inf f16 pair
    }

    for (int c = 0; c < 64; c++) {
        // stage 64 rows of h (32 KB), fully coalesced
        const uint4* hs = (const uint4*)(h + c * 64 * 256);
        uint4* hd = (uint4*)hch;
#pragma unroll
        for (int i = 0; i < 8; i++) hd[t + i * 256] = hs[t + i * 256];
        __syncthreads();

        unsigned w0[4], w1[4];
#pragma unroll
        for (int e = 0; e < 4; e++) {
            w0[e] = (unsigned)__builtin_amdgcn_readfirstlane((int)bits[(wv * 4 + e) * 128 + 2 * c]);
            w1[e] = (unsigned)__builtin_amdgcn_readfirstlane((int)bits[(wv * 4 + e) * 128 + 2 * c + 1]);
        }

#pragma unroll
        for (int nn = 0; nn < 32; nn++) {
            uint2 v = *(const uint2*)(hch + nn * 256 + l * 4);
#pragma unroll
            for (int e = 0; e < 4; e++) {
                if ((w0[e] >> nn) & 1u) {   // wave-uniform scalar branch
                    pkmaxmin(mx[e][0], mn[e][0], v.x);
                    pkmaxmin(mx[e][1], mn[e][1], v.y);
                }
            }
        }
#pragma unroll
        for (int nn = 0; nn < 32; nn++) {
            uint2 v = *(const uint2*)(hch + (nn + 32) * 256 + l * 4);
#pragma unroll
            for (int e = 0; e < 4; e++) {
                if ((w1[e] >> nn) & 1u) {
                    pkmaxmin(mx[e][0], mn[e][0], v.x);
                    pkmaxmin(mx[e][1], mn[e][1], v.y);
                }
            }
        }
        __syncthreads();
    }

    // epilogue: pooled = max - min; score = sigmoid(pooled . Wscore + b)
    float4 wsv = ((const float4*)Wscore)[l];   // f32 cols 4l..4l+3
    const float bsc = *bscore;
#pragma unroll
    for (int e = 0; e < 4; e++) {
        float s = (f16u_to_f(mx[e][0])       - f16u_to_f(mn[e][0]))       * wsv.x
                + (f16u_to_f(mx[e][0] >> 16) - f16u_to_f(mn[e][0] >> 16)) * wsv.y
                + (f16u_to_f(mx[e][1])       - f16u_to_f(mn[e][1]))       * wsv.z
                + (f16u_to_f(mx[e][1] >> 16) - f16u_to_f(mn[e][1] >> 16)) * wsv.w;
#pragma unroll
        for (int off = 32; off; off >>= 1) s += __shfl_xor(s, off);
        if (l == 0) {
            float sig = 1.f / (1.f + __expf(-(s + bsc)));
            out[br * 4096 + e0 + wv * 4 + e] = sig;
        }
    }
}

// ---------------------------------------------------------------- launch
extern "C" void kernel_launch(void* const* d_in, const int* in_sizes, int n_in,
                              void* d_out, int out_size, void* d_ws, size_t ws_size,
                              hipStream_t stream) {
    const float* pf  = (const float*)d_in[0];
    const float* pm  = (const float*)d_in[1];
    const float* nf  = (const float*)d_in[2];
    const float* nm  = (const float*)d_in[3];
    const int*   msk = (const int*)d_in[4];
    const float* Wsf = (const float*)d_in[5];
    const float* bsf = (const float*)d_in[6];
    const float* Whp = (const float*)d_in[7];
    const float* bhp = (const float*)d_in[8];
    const float* Wsc = (const float*)d_in[9];
    const float* bsc = (const float*)d_in[10];
    float* out = (float*)d_out;

    char* ws = (char*)d_ws;
    unsigned short* hbuf = (unsigned short*)ws;                              // 4 MB (f16 h, 2 branches)
    unsigned short* Wts  = (unsigned short*)(ws + 4u * 1024 * 1024);         // 128 KB
    unsigned short* Wth  = Wts + 256 * 256;                                  // 128 KB
    unsigned*       pck  = (unsigned*)(ws + 4u * 1024 * 1024 + 512u * 1024); // 2 MB

    k_transpose<<<dim3(256, 2), 256, 0, stream>>>(Wsf, Whp, Wts, Wth);
    k_pack_mask<<<2048, 256, 0, stream>>>(msk, pck);
    k_gemm_relu<<<dim3(64, 4, 2), 256, 0, stream>>>(pf, pm, nf, nm, Wts, Wth, bsf, bhp, hbuf);
    k_pool_score<<<dim3(256, 2), 256, 0, stream>>>(hbuf, pck, Wsc, bsc, out);
}

// Round 3
// 725.718 us; speedup vs baseline: 1.6093x; 1.6093x over previous
//
#include <hip/hip_runtime.h>
#include <hip/hip_bf16.h>
#include <hip/hip_fp16.h>

// N=4096 nodes, E=4096 hyperedges, F=256, H=256. All float tensors f32;
// batch_mask int32. out = 8192 f32: [pos_score | neg_score].

typedef short bf16x8 __attribute__((ext_vector_type(8)));
typedef float f32x4 __attribute__((ext_vector_type(4)));
typedef unsigned short u16x2 __attribute__((ext_vector_type(2)));

static __device__ __forceinline__ unsigned short f2bf(float f) {
    __hip_bfloat16 b = __float2bfloat16(f);
    return __builtin_bit_cast(unsigned short, b);
}
static __device__ __forceinline__ float f16u_to_f(unsigned u) {
    __half h = __builtin_bit_cast(__half, (unsigned short)(u & 0xffffu));
    return __half2float(h);
}
static __device__ __forceinline__ unsigned pkmax(unsigned a, unsigned b) {
    u16x2 r = __builtin_elementwise_max(__builtin_bit_cast(u16x2, a), __builtin_bit_cast(u16x2, b));
    return __builtin_bit_cast(unsigned, r);
}
static __device__ __forceinline__ unsigned pkmin(unsigned a, unsigned b) {
    u16x2 r = __builtin_elementwise_min(__builtin_bit_cast(u16x2, a), __builtin_bit_cast(u16x2, b));
    return __builtin_bit_cast(unsigned, r);
}

// ---------------------------------------------------------------- transpose W (f32 -> bf16)
__global__ void k_transpose(const float* __restrict__ Ws, const float* __restrict__ Wh,
                            unsigned short* __restrict__ Wts, unsigned short* __restrict__ Wth) {
    int k = blockIdx.x;
    int n = threadIdx.x;
    const float* W     = blockIdx.y ? Wh : Ws;
    unsigned short* Wt = blockIdx.y ? Wth : Wts;
    Wt[n * 256 + k] = f2bf(W[k * 256 + n]);
}

// ---------------------------------------------------------------- pack mask -> bitwords
// packed[e][i] bit j = mask[e][i*32+j]
__global__ void k_pack_mask(const int* __restrict__ mask, unsigned* __restrict__ packed) {
    int w = blockIdx.x * 256 + threadIdx.x;
    const int* p = mask + (size_t)w * 32;
    unsigned word = 0;
#pragma unroll
    for (int j = 0; j < 32; j += 4) {
        int4 m = *(const int4*)(p + j);
        word |= (m.x != 0 ? (1u << j) : 0u)
              | (m.y != 0 ? (1u << (j + 1)) : 0u)
              | (m.z != 0 ? (1u << (j + 2)) : 0u)
              | (m.w != 0 ? (1u << (j + 3)) : 0u);
    }
    packed[w] = word;
}

// ---------------------------------------------------------------- GEMM + relu -> f16 h
__launch_bounds__(256)
__global__ void k_gemm_relu(const float* __restrict__ pXf, const float* __restrict__ pXm,
                            const float* __restrict__ nXf, const float* __restrict__ nXm,
                            const unsigned short* __restrict__ Wts, const unsigned short* __restrict__ Wth,
                            const float* __restrict__ bs,  const float* __restrict__ bh,
                            unsigned short* __restrict__ hAll /* f16 [2][4096][256] */) {
    const int t  = threadIdx.x;
    const int wv = t >> 6;
    const int l  = t & 63;
    const int lm = l & 15;
    const int q  = l >> 4;
    const int bz = blockIdx.z;
    const float* Xf = bz ? nXf : pXf;
    const float* Xm = bz ? nXm : pXm;
    unsigned short* hb = hAll + (size_t)bz * 4096 * 256;

    const int m0 = blockIdx.x * 64 + wv * 16;
    const int n0 = blockIdx.y * 64;

    f32x4 acc[4] = {};
#pragma unroll
    for (int ks = 0; ks < 512; ks += 32) {
        const float* X           = (ks < 256) ? Xf : Xm;
        const unsigned short* Wt = (ks < 256) ? Wts : Wth;
        const int kk = (ks & 255) + q * 8;
        float4 a0 = *(const float4*)(X + (m0 + lm) * 256 + kk);
        float4 a1 = *(const float4*)(X + (m0 + lm) * 256 + kk + 4);
        bf16x8 a;
        a[0] = (short)f2bf(a0.x); a[1] = (short)f2bf(a0.y);
        a[2] = (short)f2bf(a0.z); a[3] = (short)f2bf(a0.w);
        a[4] = (short)f2bf(a1.x); a[5] = (short)f2bf(a1.y);
        a[6] = (short)f2bf(a1.z); a[7] = (short)f2bf(a1.w);
#pragma unroll
        for (int nt = 0; nt < 4; nt++) {
            bf16x8 b = *(const bf16x8*)(Wt + (n0 + nt * 16 + lm) * 256 + kk);
            acc[nt] = __builtin_amdgcn_mfma_f32_16x16x32_bf16(a, b, acc[nt], 0, 0, 0);
        }
    }
#pragma unroll
    for (int nt = 0; nt < 4; nt++) {
        const int c = n0 + nt * 16 + lm;
        const float bsum = bs[c] + bh[c];
#pragma unroll
        for (int i = 0; i < 4; i++) {
            const int r = m0 + q * 4 + i;
            float v = acc[nt][i] + bsum;
            v = v > 0.f ? v : 0.f;   // relu => h >= +0.0 (u16-monotonic f16 bits)
            hb[r * 256 + c] = __builtin_bit_cast(unsigned short, __float2half(v));
        }
    }
}

// ---------------------------------------------------------------- pool (branchless) + partial dot
// Block: 32 edges x 128 cols (one col-half) x one branch, scanning all 4096 nodes.
// 4 waves; wave wv owns edges wv*8..wv*8+7. Lane l holds col-pair (2*l, 2*l+1)
// of the half. Mask select folded into SGPR operands (s_cselect -> v_and / v_or),
// NO branches. h staged in LDS 64 nodes x 128 cols (16KB) per chunk.
// grid (128 edge-groups, 2 col-halves, 2 branches), block 256.
__launch_bounds__(256)
__global__ void k_pool2(const unsigned short* __restrict__ hAll,
                        const unsigned* __restrict__ packed,
                        const float* __restrict__ Wscore,
                        float* __restrict__ pdot /* [2][4096][2] */) {
    __shared__ __align__(16) unsigned bits[32 * 128];   // 16 KB
    __shared__ __align__(16) unsigned hch[64 * 64];     // 16 KB (64 nodes x 128 cols f16)

    const int t    = threadIdx.x;
    const int wv   = t >> 6;
    const int l    = t & 63;
    const int e0   = blockIdx.x * 32;
    const int half = blockIdx.y;
    const int br   = blockIdx.z;
    const unsigned short* h = hAll + (size_t)br * 4096 * 256;

    {   // stage mask bits for 32 edges: 4096 u32 = 16 KB
        const uint4* src = (const uint4*)(packed + e0 * 128);
        uint4* dst = (uint4*)bits;
#pragma unroll
        for (int i = 0; i < 4; i++) dst[t + i * 256] = src[t + i * 256];
    }

    unsigned mx[8], mn[8];
#pragma unroll
    for (int e = 0; e < 8; e++) { mx[e] = 0u; mn[e] = 0x7C007C00u; }

    const int r  = t >> 4;      // staging row 0..15
    const int sg = t & 15;      // staging 16B segment 0..15

    for (int ch = 0; ch < 64; ch++) {
        // stage 64 rows x 128 cols (16 KB); each pass: 16 full rows
#pragma unroll
        for (int p = 0; p < 4; p++) {
            const int row = ch * 64 + r + p * 16;
            *(uint4*)&hch[(r + p * 16) * 64 + sg * 4] =
                *(const uint4*)(h + (size_t)row * 256 + half * 128 + sg * 8);
        }
        __syncthreads();

#pragma unroll
        for (int w2 = 0; w2 < 2; w2++) {
            unsigned wd[8];
#pragma unroll
            for (int e = 0; e < 8; e++)
                wd[e] = (unsigned)__builtin_amdgcn_readfirstlane(
                            (int)bits[(wv * 8 + e) * 128 + ch * 2 + w2]);
#pragma unroll
            for (int j = 0; j < 32; j++) {
                unsigned v = hch[(w2 * 32 + j) * 64 + l];
#pragma unroll
                for (int e = 0; e < 8; e++) {
                    const unsigned bit = (wd[e] >> j) & 1u;
                    const unsigned m   = bit ? 0xFFFFFFFFu : 0u;          // s_cselect
                    const unsigned mi  = bit ? 0u : 0x7C007C00u;          // s_cselect
                    mx[e] = pkmax(mx[e], v & m);    // nonmember -> 0 (identity, h>=0)
                    mn[e] = pkmin(mn[e], v | mi);   // nonmember -> >=inf pattern
                }
            }
        }
        __syncthreads();
    }

    // partial dot over this col-half: sum_c (mx-mn)*Wscore[c]
    float2 wsv = *(const float2*)(Wscore + half * 128 + 2 * l);
#pragma unroll
    for (int e = 0; e < 8; e++) {
        float d0 = f16u_to_f(mx[e])       - f16u_to_f(mn[e]);
        float d1 = f16u_to_f(mx[e] >> 16) - f16u_to_f(mn[e] >> 16);
        float s = d0 * wsv.x + d1 * wsv.y;
#pragma unroll
        for (int off = 32; off; off >>= 1) s += __shfl_xor(s, off);
        if (l == 0)
            pdot[((size_t)br * 4096 + e0 + wv * 8 + e) * 2 + half] = s;
    }
}

// ---------------------------------------------------------------- finisher
__global__ void k_score(const float* __restrict__ pdot, const float* __restrict__ bscore,
                        float* __restrict__ out) {
    int i = blockIdx.x * 256 + threadIdx.x;   // 0..8191
    float s = pdot[2 * i] + pdot[2 * i + 1] + bscore[0];
    out[i] = 1.f / (1.f + __expf(-s));
}

// ---------------------------------------------------------------- launch
extern "C" void kernel_launch(void* const* d_in, const int* in_sizes, int n_in,
                              void* d_out, int out_size, void* d_ws, size_t ws_size,
                              hipStream_t stream) {
    const float* pf  = (const float*)d_in[0];
    const float* pm  = (const float*)d_in[1];
    const float* nf  = (const float*)d_in[2];
    const float* nm  = (const float*)d_in[3];
    const int*   msk = (const int*)d_in[4];
    const float* Wsf = (const float*)d_in[5];
    const float* bsf = (const float*)d_in[6];
    const float* Whp = (const float*)d_in[7];
    const float* bhp = (const float*)d_in[8];
    const float* Wsc = (const float*)d_in[9];
    const float* bsc = (const float*)d_in[10];
    float* out = (float*)d_out;

    char* ws = (char*)d_ws;
    unsigned short* hbuf = (unsigned short*)ws;                                   // 4 MB
    unsigned short* Wts  = (unsigned short*)(ws + 4u * 1024 * 1024);              // 128 KB
    unsigned short* Wth  = Wts + 256 * 256;                                       // 128 KB
    unsigned*       pck  = (unsigned*)(ws + 4u * 1024 * 1024 + 512u * 1024);      // 2 MB
    float*          pdot = (float*)(ws + 6u * 1024 * 1024 + 512u * 1024);         // 64 KB

    k_transpose<<<dim3(256, 2), 256, 0, stream>>>(Wsf, Whp, Wts, Wth);
    k_pack_mask<<<2048, 256, 0, stream>>>(msk, pck);
    k_gemm_relu<<<dim3(64, 4, 2), 256, 0, stream>>>(pf, pm, nf, nm, Wts, Wth, bsf, bhp, hbuf);
    k_pool2<<<dim3(128, 2, 2), 256, 0, stream>>>(hbuf, pck, Wsc, pdot);
    k_score<<<32, 256, 0, stream>>>(pdot, bsc, out);
}